// Round 11
// baseline (183.768 us; speedup 1.0000x reference)
//
#include <hip/hip_runtime.h>

// Causal MHA forward, B=2 T=2048 C=1024 H=16 hs=64, fp32 in/out, bf16 MFMA internally.
// R11: transposed-output epilogues. A/B operand per-lane layouts are identical for
// mfma_16x16x32, so swapping operands computes D^T free: acc regs then run along the
// memory-contiguous dim -> qkv 16x 8B stores (was 64x 2B), proj float4 stores,
// flash O^T (4x 8B stores, no normalization shuffles). All else identical to R10.

typedef unsigned short u16;
typedef unsigned int u32;
typedef __bf16 bf16x8 __attribute__((ext_vector_type(8)));
typedef float f32x4 __attribute__((ext_vector_type(4)));
typedef u32 u32x4 __attribute__((ext_vector_type(4)));
typedef u16 u16x4 __attribute__((ext_vector_type(4)));

__device__ __forceinline__ u16 f2bf(float f) {
  u32 u = __float_as_uint(f);
  u32 r = u + 0x7FFFu + ((u >> 16) & 1u);  // RNE, finite inputs only
  return (u16)(r >> 16);
}

__device__ __forceinline__ bf16x8 ld_bf8(const u16* p) {
  union { u32x4 u; bf16x8 b; } x;
  x.u = *(const u32x4*)p;
  return x.b;
}

__device__ __forceinline__ void gld_lds16(const u16* g, u16* l) {
  __builtin_amdgcn_global_load_lds(
      (const __attribute__((address_space(1))) u32*)g,
      (__attribute__((address_space(3))) u32*)l, 16, 0, 0);
}

// ---- merged prep: fp32->bf16 x-convert + both weight transpose-converts ----
__device__ __forceinline__ void convT_body(const float* __restrict__ src,
                                           u16* __restrict__ dst, int R, int Cc,
                                           int r0, int c0, float* ls /*64x65*/) {
  int t = threadIdx.x;
  for (int u = t; u < 1024; u += 256) {
    int r = u >> 4, cs = (u & 15) << 2;
    float4 v = *(const float4*)&src[(size_t)(r0 + r) * Cc + (c0 + cs)];
    ls[r * 65 + cs] = v.x; ls[r * 65 + cs + 1] = v.y;
    ls[r * 65 + cs + 2] = v.z; ls[r * 65 + cs + 3] = v.w;
  }
  __syncthreads();
  for (int u = t; u < 1024; u += 256) {
    int n = u >> 4, ks = (u & 15) << 2;
    u16x4 o;
    o.x = f2bf(ls[ks * 65 + n]); o.y = f2bf(ls[(ks + 1) * 65 + n]);
    o.z = f2bf(ls[(ks + 2) * 65 + n]); o.w = f2bf(ls[(ks + 3) * 65 + n]);
    *(u16x4*)&dst[(size_t)(c0 + n) * R + (r0 + ks)] = o;
  }
}

__global__ __launch_bounds__(256) void prep_kernel(
    const float* __restrict__ x, const float* __restrict__ Wkqv,
    const float* __restrict__ Wproj, u16* __restrict__ xb,
    u16* __restrict__ wkqvT, u16* __restrict__ wprojT) {
  __shared__ float ls[64 * 65];
  int bx = blockIdx.x;
  if (bx < 2048) {  // x -> bf16, 8 elems/thread
    int idx = bx * 256 + threadIdx.x;
    const float4* s4 = (const float4*)x;
    float4 a = s4[2 * idx], b = s4[2 * idx + 1];
    union { u16 h[8]; u32x4 v; } pk;
    pk.h[0] = f2bf(a.x); pk.h[1] = f2bf(a.y); pk.h[2] = f2bf(a.z); pk.h[3] = f2bf(a.w);
    pk.h[4] = f2bf(b.x); pk.h[5] = f2bf(b.y); pk.h[6] = f2bf(b.z); pk.h[7] = f2bf(b.w);
    *(u32x4*)&xb[(size_t)idx * 8] = pk.v;
  } else if (bx < 2816) {  // W_kqv^T (1024x3072 -> 3072x1024)
    int idx = bx - 2048;
    convT_body(Wkqv, wkqvT, 1024, 3072, (idx & 15) * 64, (idx >> 4) * 64, ls);
  } else {                 // W_proj^T (1024x1024 -> 1024x1024)
    int idx = bx - 2816;
    convT_body(Wproj, wprojT, 1024, 1024, (idx & 15) * 64, (idx >> 4) * 64, ls);
  }
}

// ---- QKV GEMM: 128x128 tile, 4 waves x (64ch x 64tok), BK=32, K=1024 ----
// D^T form: A=weight-frag, B=x-frag -> lane holds 4 consecutive channels at fixed token
// -> epilogue is 16 u16x4 (8B) stores per lane.
__global__ __launch_bounds__(256) void qkv_gemm_kernel(
    const u16* __restrict__ A, const u16* __restrict__ Bt,
    u16* __restrict__ Qh, u16* __restrict__ Kh, u16* __restrict__ Vh, float qscale) {
  constexpr int K = 1024;
  __shared__ __align__(16) u16 As[128 * 32];  // token rows
  __shared__ __align__(16) u16 Bs[128 * 32];  // weight rows
  int t = threadIdx.x;
  int wave = t >> 6, lane = t & 63, quad = lane >> 4, l16 = lane & 15;
  int wch = (wave >> 1) << 6, wtk = (wave & 1) << 6;
  int tok0 = blockIdx.x * 128, ch0 = blockIdx.y * 128;
  f32x4 acc[4][4] = {};  // [channel strip][token strip]
  int u0 = t, u1 = t + 256;
  int ra0 = u0 >> 2, ca0 = ((u0 & 3) ^ ((u0 >> 3) & 3)) << 3;
  int ra1 = u1 >> 2, ca1 = ((u1 & 3) ^ ((u1 >> 3) & 3)) << 3;
  int swq = (quad ^ ((l16 >> 1) & 3)) << 3;
  for (int k0 = 0; k0 < K; k0 += 32) {
    gld_lds16(&A[(size_t)(tok0 + ra0) * K + k0 + ca0], &As[u0 * 8]);
    gld_lds16(&A[(size_t)(tok0 + ra1) * K + k0 + ca1], &As[u1 * 8]);
    gld_lds16(&Bt[(size_t)(ch0 + ra0) * K + k0 + ca0], &Bs[u0 * 8]);
    gld_lds16(&Bt[(size_t)(ch0 + ra1) * K + k0 + ca1], &Bs[u1 * 8]);
    __syncthreads();
    bf16x8 af[4], bfr[4];
    for (int r = 0; r < 4; ++r) af[r] = ld_bf8(&Bs[(wch + r * 16 + l16) * 32 + swq]);
    for (int c = 0; c < 4; ++c) bfr[c] = ld_bf8(&As[(wtk + c * 16 + l16) * 32 + swq]);
    for (int r = 0; r < 4; ++r)
      for (int c = 0; c < 4; ++c)
        acc[r][c] = __builtin_amdgcn_mfma_f32_16x16x32_bf16(af[r], bfr[c], acc[r][c], 0, 0, 0);
    __syncthreads();
  }
  for (int r = 0; r < 4; ++r) {
    int col = ch0 + wch + r * 16 + quad * 4;  // channel base (4-aligned, head-safe)
    int seg = col >> 10, cc = col & 1023;
    int h = cc >> 6, d0 = cc & 63;
    u16* dst = (seg == 0) ? Qh : (seg == 1) ? Kh : Vh;
    float sc = (seg == 0) ? qscale : 1.0f;
    for (int c = 0; c < 4; ++c) {
      int tt = tok0 + wtk + c * 16 + l16;
      int b = tt >> 11, t2 = tt & 2047;
      union { u16 hh[4]; u16x4 v; } pk;
      for (int i = 0; i < 4; ++i) pk.hh[i] = f2bf(acc[r][c][i] * sc);
      *(u16x4*)&dst[(((size_t)(b * 16 + h)) * 2048 + t2) * 64 + d0] = pk.v;
    }
  }
}

// ---- bf16 transpose: Vh[bh][2048][64] -> Vt[bh][64][2048] ----
__global__ __launch_bounds__(256) void vT_kernel(const u16* __restrict__ Vh,
                                                 u16* __restrict__ Vt) {
  __shared__ __align__(16) u16 ls[64 * 72];
  int t = threadIdx.x;
  int t0 = blockIdx.x * 64, bh = blockIdx.y;
  const u16* in = Vh + ((size_t)bh * 2048 + t0) * 64;
  for (int u = t; u < 512; u += 256) {
    int row = u >> 3, col = (u & 7) << 3;
    *(u32x4*)&ls[row * 72 + col] = *(const u32x4*)&in[(size_t)row * 64 + col];
  }
  __syncthreads();
  for (int u = t; u < 512; u += 256) {
    int d = u >> 3, tc = (u & 7) << 3;
    union { u16 h[8]; u32x4 v; } pk;
    for (int j = 0; j < 8; ++j) pk.h[j] = ls[(tc + j) * 72 + d];
    *(u32x4*)&Vt[((size_t)bh * 64 + d) * 2048 + t0 + tc] = pk.v;
  }
}

// ---- proj GEMM: 64x64 tile, 4 waves (2x2), grid (64,16); D^T -> float4 stores ----
__global__ __launch_bounds__(256) void proj_gemm_kernel(
    const u16* __restrict__ A, const u16* __restrict__ Bt,
    float* __restrict__ out, const float* __restrict__ bias) {
  constexpr int K = 1024;
  __shared__ __align__(16) u16 As[64 * 32];  // token rows
  __shared__ __align__(16) u16 Bs[64 * 32];  // weight rows
  int t = threadIdx.x;
  int wave = t >> 6, lane = t & 63, quad = lane >> 4, l16 = lane & 15;
  int wch = (wave >> 1) << 5, wtk = (wave & 1) << 5;
  int tok0 = blockIdx.x * 64, ch0 = blockIdx.y * 64;
  f32x4 acc[2][2] = {};
  int u0 = t;
  int ra0 = u0 >> 2, ca0 = ((u0 & 3) ^ ((u0 >> 3) & 3)) << 3;
  int swq = (quad ^ ((l16 >> 1) & 3)) << 3;
  for (int k0 = 0; k0 < K; k0 += 32) {
    gld_lds16(&A[(size_t)(tok0 + ra0) * K + k0 + ca0], &As[u0 * 8]);
    gld_lds16(&Bt[(size_t)(ch0 + ra0) * K + k0 + ca0], &Bs[u0 * 8]);
    __syncthreads();
    bf16x8 af[2], bfr[2];
    for (int r = 0; r < 2; ++r) af[r] = ld_bf8(&Bs[(wch + r * 16 + l16) * 32 + swq]);
    for (int c = 0; c < 2; ++c) bfr[c] = ld_bf8(&As[(wtk + c * 16 + l16) * 32 + swq]);
    for (int r = 0; r < 2; ++r)
      for (int c = 0; c < 2; ++c)
        acc[r][c] = __builtin_amdgcn_mfma_f32_16x16x32_bf16(af[r], bfr[c], acc[r][c], 0, 0, 0);
    __syncthreads();
  }
  for (int r = 0; r < 2; ++r) {
    int col = ch0 + wch + r * 16 + quad * 4;
    float4 bv = *(const float4*)&bias[col];
    for (int c = 0; c < 2; ++c) {
      int tt = tok0 + wtk + c * 16 + l16;
      float4 o;
      o.x = acc[r][c][0] + bv.x; o.y = acc[r][c][1] + bv.y;
      o.z = acc[r][c][2] + bv.z; o.w = acc[r][c][3] + bv.w;
      *(float4*)&out[(size_t)tt * 1024 + col] = o;
    }
  }
}

// ---- flash attention: BQ=64, 4 waves x 16 q-rows, S^T QK + O^T PV ----
// PV operand swap: oacc = mfma(vb, pa) -> lane holds q=l16 (matches lsum indexing,
// no shuffles) and 4 consecutive d per reg -> 8B stores / float4 partials.
__global__ __launch_bounds__(256, 6) void flash_kernel(
    const u16* __restrict__ Qh, const u16* __restrict__ Kh, const u16* __restrict__ Vt,
    u16* __restrict__ yb, float* __restrict__ Opart) {
  __shared__ __align__(16) u16 Ks[64 * 64];
  __shared__ __align__(16) u16 Vs[64 * 64];
  __shared__ __align__(16) u16 Ps[64 * 64];
  int t = threadIdx.x, wave = t >> 6, lane = t & 63, quad = lane >> 4, l16 = lane & 15;
  int id = blockIdx.x;                 // 0..1439
  int g = id / 360, r = id % 360;
  int bh = g * 8 + (r & 7);            // same-bh jobs share an XCD
  int jx = r >> 3;                     // 0..44, longest first
  int qtile, kvs, kve, sidx = 0, half = 0;
  bool partial;
  if (jx < 19) {                       // full jobs: qtile 18..0
    qtile = 18 - jx; kvs = 0; kve = qtile + 1; partial = false;
  } else {                             // split jobs: qtile 31..19, 2 halves (<=16 iters)
    sidx = (jx - 19) >> 1; half = (jx - 19) & 1;
    qtile = 31 - sidx;
    int nkv = qtile + 1, mid = nkv >> 1;
    kvs = half ? mid : 0; kve = half ? nkv : mid; partial = true;
  }
  int q0 = qtile << 6;
  const u16* Qb = Qh + (size_t)bh * 2048 * 64;
  const u16* Kb = Kh + (size_t)bh * 2048 * 64;
  const u16* Vb = Vt + (size_t)bh * 64 * 2048;
  bf16x8 qa0, qa1;  // B-operand frags (S^T form)
  {
    int qrow = q0 + wave * 16 + l16;
    qa0 = ld_bf8(&Qb[(size_t)qrow * 64 + quad * 8]);
    qa1 = ld_bf8(&Qb[(size_t)qrow * 64 + 32 + quad * 8]);
  }
  f32x4 oacc[4] = {};
  float lsum = 0.f;
  int u0 = wave * 128 + lane, u1 = u0 + 64;
  int r0 = u0 >> 3, p0 = u0 & 7, cb0 = (p0 - r0) & 7;
  int r1s = u1 >> 3, p1 = u1 & 7, cb1 = (p1 - r1s) & 7;
  for (int j = kvs; j < kve; ++j) {
    int kv0 = j << 6;
    __syncthreads();  // previous tile fully consumed
    gld_lds16(&Kb[(size_t)(kv0 + r0) * 64 + cb0 * 8], &Ks[u0 * 8]);
    gld_lds16(&Kb[(size_t)(kv0 + r1s) * 64 + cb1 * 8], &Ks[u1 * 8]);
    gld_lds16(&Vb[(size_t)r0 * 2048 + kv0 + cb0 * 8], &Vs[u0 * 8]);
    gld_lds16(&Vb[(size_t)r1s * 2048 + kv0 + cb1 * 8], &Vs[u1 * 8]);
    __syncthreads();  // vmcnt drain -> tiles ready
    bool maskit = (j == qtile);
    for (int c = 0; c < 4; ++c) {
      int krow = c * 16 + l16;
      bf16x8 kb0 = ld_bf8(&Ks[krow * 64 + ((quad + krow) & 7) * 8]);
      bf16x8 kb1 = ld_bf8(&Ks[krow * 64 + ((quad + 4 + krow) & 7) * 8]);
      f32x4 z = {0.f, 0.f, 0.f, 0.f};
      z = __builtin_amdgcn_mfma_f32_16x16x32_bf16(kb0, qa0, z, 0, 0, 0);
      z = __builtin_amdgcn_mfma_f32_16x16x32_bf16(kb1, qa1, z, 0, 0, 0);
      int prow = wave * 16 + l16;
      union { u16 hh[4]; u16x4 v; } pk;
      if (maskit) {
        int qg = q0 + prow;
        for (int i = 0; i < 4; ++i) {
          float p = __builtin_amdgcn_exp2f(z[i]);
          if (kv0 + c * 16 + quad * 4 + i > qg) p = 0.f;
          lsum += p;
          pk.hh[i] = f2bf(p);
        }
      } else {
        for (int i = 0; i < 4; ++i) {
          float p = __builtin_amdgcn_exp2f(z[i]);
          lsum += p;
          pk.hh[i] = f2bf(p);
        }
      }
      *(u16x4*)&Ps[prow * 64 + ((2 * c + (quad >> 1) + prow) & 7) * 8 + (quad & 1) * 4] = pk.v;
    }
    int prow = wave * 16 + l16;
    bf16x8 pa0 = ld_bf8(&Ps[prow * 64 + ((quad + prow) & 7) * 8]);      // P[q][kv] A-layout
    bf16x8 pa1 = ld_bf8(&Ps[prow * 64 + ((quad + 4 + prow) & 7) * 8]);
    for (int dt = 0; dt < 4; ++dt) {
      int vrow = dt * 16 + l16;
      bf16x8 vb0 = ld_bf8(&Vs[vrow * 64 + ((quad + vrow) & 7) * 8]);
      bf16x8 vb1 = ld_bf8(&Vs[vrow * 64 + ((quad + 4 + vrow) & 7) * 8]);
      // O^T: A=V^T-frag, B=P^T-frag (same per-lane layouts as the A-reads above)
      oacc[dt] = __builtin_amdgcn_mfma_f32_16x16x32_bf16(vb0, pa0, oacc[dt], 0, 0, 0);
      oacc[dt] = __builtin_amdgcn_mfma_f32_16x16x32_bf16(vb1, pa1, oacc[dt], 0, 0, 0);
    }
  }
  lsum += __shfl_xor(lsum, 16);
  lsum += __shfl_xor(lsum, 32);
  // oacc[dt][i]: q = q0 + wave*16 + l16 (own lane), d = dt*16 + quad*4 + i
  if (partial) {
    float* Op = Opart + ((size_t)(bh * 13 + sidx) * 2 + half) * 4160;
    int q = wave * 16 + l16;
    for (int dt = 0; dt < 4; ++dt)
      *(f32x4*)&Op[q * 64 + dt * 16 + quad * 4] = oacc[dt];
    if (quad == 0) Op[4096 + q] = lsum;
  } else {
    int b = bh >> 4, h = bh & 15;
    float inv = 1.0f / lsum;
    int qq = q0 + wave * 16 + l16;
    size_t rowoff = ((size_t)(b * 2048 + qq)) * 1024 + h * 64;
    for (int dt = 0; dt < 4; ++dt) {
      union { u16 hh[4]; u16x4 v; } pk;
      for (int i = 0; i < 4; ++i) pk.hh[i] = f2bf(oacc[dt][i] * inv);
      *(u16x4*)&yb[rowoff + dt * 16 + quad * 4] = pk.v;
    }
  }
}

// ---- combine split halves: O = O0+O1, l = l0+l1, write normalized bf16 ----
__global__ __launch_bounds__(256) void combine_kernel(const float* __restrict__ Opart,
                                                      u16* __restrict__ yb) {
  int sidx = blockIdx.x, bh = blockIdx.y, t = threadIdx.x;
  int qtile = 31 - sidx;
  const float* A = Opart + (size_t)(bh * 13 + sidx) * 2 * 4160;
  const float* Bp = A + 4160;
  int q = t >> 2, d0 = (t & 3) << 4;
  float inv = 1.0f / (A[4096 + q] + Bp[4096 + q]);
  int b = bh >> 4, h = bh & 15;
  size_t off = ((size_t)(b * 2048 + (qtile << 6) + q)) * 1024 + h * 64 + d0;
  union { u16 hh[16]; u32x4 v[2]; } pk;
  for (int k = 0; k < 16; ++k)
    pk.hh[k] = f2bf((A[q * 64 + d0 + k] + Bp[q * 64 + d0 + k]) * inv);
  *(u32x4*)&yb[off] = pk.v[0];
  *(u32x4*)&yb[off + 8] = pk.v[1];
}

extern "C" void kernel_launch(void* const* d_in, const int* in_sizes, int n_in,
                              void* d_out, int out_size, void* d_ws, size_t ws_size,
                              hipStream_t stream) {
  const float* x     = (const float*)d_in[0];
  const float* Wkqv  = (const float*)d_in[1];
  const float* Wproj = (const float*)d_in[2];
  const float* bproj = (const float*)d_in[3];
  float* out = (float*)d_out;

  u16* ws     = (u16*)d_ws;                       // 48 MiB total scratch
  u16* xb     = ws;                               // 4096x1024 bf16 = 8.39 MB (dead after qkv)
  u16* wkqvT  = xb + (size_t)4096 * 1024;         // 3072x1024 = 6.29 MB (dead after qkv)
  u16* wprojT = wkqvT + (size_t)3072 * 1024;      // 1024x1024 (W_proj^T) -- LIVE to the end
  u16* Qh     = wprojT + (size_t)1024 * 1024;     // [32][2048][64], pre-scaled
  u16* Kh     = Qh + (size_t)32 * 2048 * 64;      // [32][2048][64]
  u16* Vt     = Kh + (size_t)32 * 2048 * 64;      // [32][64][2048]
  u16* yb     = Vt + (size_t)32 * 2048 * 64;      // 4096x1024 attn out; doubles as Vh
  u16* Vh     = yb;
  // Opart: 32 bh x 13 split-tiles x 2 halves x 4160 fp32 = 13.84 MB — inside dead
  // xb+wkqvT (14.68 MB); wprojT untouched.
  float* Opart = (float*)ws;

  const float QSCALE = 0.18033688011112042f;  // (1/sqrt(64)) * log2(e)

  prep_kernel<<<3072, 256, 0, stream>>>(x, Wkqv, Wproj, xb, wkqvT, wprojT);
  qkv_gemm_kernel<<<dim3(32, 24), 256, 0, stream>>>(xb, wkqvT, Qh, Kh, Vh, QSCALE);
  vT_kernel<<<dim3(32, 32), 256, 0, stream>>>(Vh, Vt);
  flash_kernel<<<1440, 256, 0, stream>>>(Qh, Kh, Vt, yb, Opart);
  combine_kernel<<<dim3(13, 32), 256, 0, stream>>>(Opart, yb);
  proj_gemm_kernel<<<dim3(64, 16), 256, 0, stream>>>(yb, wprojT, out, bproj);
}